// Round 13
// baseline (750.062 us; speedup 1.0000x reference)
//
#include <hip/hip_runtime.h>

typedef _Float16 f16x8 __attribute__((ext_vector_type(8)));
typedef float f32x4 __attribute__((ext_vector_type(4)));
typedef float f32x16 __attribute__((ext_vector_type(16)));
typedef int i32x4 __attribute__((ext_vector_type(4)));
typedef int i32x8 __attribute__((ext_vector_type(8)));

__device__ __forceinline__ unsigned int fkey(float f) {
    unsigned int u = __float_as_uint(f);
    return u ^ ((u & 0x80000000u) ? 0xFFFFFFFFu : 0x80000000u);
}
__device__ __forceinline__ float unkey(unsigned int k) {
    unsigned int u = (k & 0x80000000u) ? (k ^ 0x80000000u) : ~k;
    return __uint_as_float(u);
}

// OCP e4m3fn encode, round-to-nearest-even (manual; known-good)
__device__ __forceinline__ unsigned int f32_to_e4m3(float f) {
    float a = fabsf(f);
    a = fminf(a, 448.0f);
    unsigned int s = (__float_as_uint(f) >> 24) & 0x80u;
    if (a < 0.015625f) {
        int m = (int)rintf(a * 512.0f);
        return s | (unsigned int)m;
    }
    int e = ilogbf(a);
    float step = ldexpf(1.0f, e - 3);
    int q = (int)rintf(a / step);
    if (q == 16) { e += 1; q = 8; }
    return s | (unsigned int)(((e + 7) << 3) | (q - 8));
}

// ============================================================
// Prep kernels (unchanged, known-good)
// ============================================================
__global__ __launch_bounds__(256) void prep_x_q(
    const float* __restrict__ x, unsigned char* __restrict__ Xq)
{
    size_t base = ((size_t)blockIdx.x * 256 + threadIdx.x) * 8;
    float4 a0 = *(const float4*)(x + base);
    float4 a1 = *(const float4*)(x + base + 4);
    float v[8] = {a0.x, a0.y, a0.z, a0.w, a1.x, a1.y, a1.z, a1.w};
    unsigned long long b = 0;
#pragma unroll
    for (int j = 0; j < 8; ++j)
        b |= (unsigned long long)f32_to_e4m3(v[j]) << (8 * j);
    *(unsigned long long*)(Xq + base) = b;
}

__global__ __launch_bounds__(256) void prep_di_q(
    const float* __restrict__ di, unsigned char* __restrict__ DqT,
    _Float16* __restrict__ DhT, _Float16* __restrict__ DlT, int D, int V)
{
    int v  = blockIdx.x * 64 + (threadIdx.x & 63);
    int d0 = blockIdx.y * 32 + (threadIdx.x >> 6) * 8;
    f16x8 h, l;
    unsigned long long b = 0;
#pragma unroll
    for (int j = 0; j < 8; ++j) {
        float val = di[(size_t)(d0 + j) * V + v];
        _Float16 hh = (_Float16)val;
        h[j] = hh;
        l[j] = (_Float16)(val - (float)hh);
        b |= (unsigned long long)f32_to_e4m3(val) << (8 * j);
    }
    *(unsigned long long*)(DqT + (size_t)v * D + d0) = b;
    *(f16x8*)(DhT + (size_t)v * D + d0) = h;
    *(f16x8*)(DlT + (size_t)v * D + d0) = l;
}

// ============================================================
// Fast pass: MX-scaled fp8 GEMM (unit scales), 256x256 tile, BK=64,
// 8 waves (2x4), per-wave 128x64 = 4x2 frags of 32x32 (r8 geometry,
// absmax-0-verified). NEW: m201-style 8-phase (4 phases/K-tile) with
// TRIPLE-buffered LDS (3 x 32KB dynamic) and ONE counted vmcnt(4) per
// K-tile (t+1's loads landed; t+2's stay in flight across barriers).
// Each phase: {ds_read A-subtile (+B at p0) || stage half of t+2 at
// p0/p2 -> s_barrier -> lgkmcnt(0)+sched_barrier -> setprio(1) 2xMFMA
// setprio(0) -> s_barrier}.  Never vmcnt(0) in the main loop.
// ============================================================
__global__ __launch_bounds__(512, 1) void gemm_mx_top2(
    const unsigned char* __restrict__ Xq, const unsigned char* __restrict__ DqT,
    unsigned long long* __restrict__ cand, int N, int D, int V)
{
    extern __shared__ __align__(16) unsigned char sm[];   // 3 x (A 16KB | B 16KB)

    const int tid = threadIdx.x;
    const int w = tid >> 6, lane = tid & 63;
    const int wr = w >> 2, wc = w & 3;            // 2x4 wave grid
    const int l31 = lane & 31, hl = lane >> 5;

    // bijective XCD swizzle (2048 blocks % 8 == 0)
    const int cpx = gridDim.x >> 3;
    const int swz = (blockIdx.x & 7) * cpx + (blockIdx.x >> 3);
    const int bm = (swz >> 5) * 256;              // 64 m-tiles
    const int bn = (swz & 31) * 256;              // 32 n-tiles

    // staging: 32 chunks/buffer (A:16, B:16), chunk = 16 rows x 64B (1KB).
    // wave w owns chunks g = w*4+i (i=0..3); op = g>>4, c = g&15.
    // lane l -> row c*16 + (l>>2), phys 16B slot l&3; source reads logical
    // slot sp ^ ((row>>1)&3) (pre-swizzle; matching XOR on ds_read).
    const int srow_in = lane >> 2;
    const int sp      = lane & 3;

    const unsigned char* srcbase[4];
    int dstoff[4];
#pragma unroll
    for (int i = 0; i < 4; ++i) {
        const int g = w * 4 + i;
        const int op = g >> 4;
        const int c  = g & 15;
        const int row = c * 16 + srow_in;
        const int slog = sp ^ ((row >> 1) & 3);
        srcbase[i] = (op ? DqT + (size_t)(bn + row) * D
                         : Xq + (size_t)(bm + row) * D) + slog * 16;
        dstoff[i] = op * 16384 + c * 1024;
    }

    // stage one HALF of a K-tile: h=0 -> chunks {0,1}, h=1 -> {2,3} (2 loads)
    auto stageH = [&](int buf, int k0, int h) {
#pragma unroll
        for (int i = 2 * h; i < 2 * h + 2; ++i) {
            __builtin_amdgcn_global_load_lds(
                (const __attribute__((address_space(1))) void*)(srcbase[i] + k0),
                (__attribute__((address_space(3))) void*)
                    (sm + buf * 32768 + dstoff[i]),
                16, 0, 0);
        }
    };
    // frag read: operand op (0=A,1=B), tile-local row r -> 32B (2 x b128)
    auto ldfrag = [&](int buf, int op, int r) -> i32x8 {
        const unsigned char* base =
            sm + buf * 32768 + op * 16384 + (r >> 4) * 1024 + (r & 15) * 64;
        const int sw = (r >> 1) & 3;
        i32x4 lo = *(const i32x4*)(base + (((hl << 1)    ) ^ sw) * 16);
        i32x4 hi = *(const i32x4*)(base + (((hl << 1) | 1) ^ sw) * 16);
        return __builtin_shufflevector(lo, hi, 0, 1, 2, 3, 4, 5, 6, 7);
    };

    f32x16 acc[4][2];
#pragma unroll
    for (int fm = 0; fm < 4; ++fm)
#pragma unroll
        for (int fn = 0; fn < 2; ++fn)
#pragma unroll
            for (int q = 0; q < 16; ++q) acc[fm][fn][q] = 0.0f;

    const int nt = D / 64;   // 32
    int cur = 0;

    // prologue: tiles 0 and 1 fully staged (8 loads/wave outstanding)
    stageH(0, 0, 0);  stageH(0, 0, 1);
    stageH(1, 64, 0); stageH(1, 64, 1);
    asm volatile("s_waitcnt vmcnt(4)" ::: "memory");   // tile 0 landed
    __builtin_amdgcn_s_barrier();

#pragma unroll 1
    for (int t = 0; t < nt; ++t) {
        const int fut = (cur >= 1) ? cur - 1 : 2;      // (cur+2)%3

        // ---------------- phase 0 (fm=0; B frags; stage half 0 of t+2) ---
        i32x8 b0 = ldfrag(cur, 1, wc * 64 + l31);
        i32x8 b1 = ldfrag(cur, 1, wc * 64 + 32 + l31);
        i32x8 a0 = ldfrag(cur, 0, wr * 128 + l31);
        if (t + 2 < nt) stageH(fut, (t + 2) * 64, 0);
        __builtin_amdgcn_s_barrier();
        asm volatile("s_waitcnt lgkmcnt(0)" ::: "memory");
        __builtin_amdgcn_sched_barrier(0);
        __builtin_amdgcn_s_setprio(1);
        acc[0][0] = __builtin_amdgcn_mfma_scale_f32_32x32x64_f8f6f4(
            a0, b0, acc[0][0], 0, 0, 0, 0x7F7F7F7F, 0, 0x7F7F7F7F);
        acc[0][1] = __builtin_amdgcn_mfma_scale_f32_32x32x64_f8f6f4(
            a0, b1, acc[0][1], 0, 0, 0, 0x7F7F7F7F, 0, 0x7F7F7F7F);
        __builtin_amdgcn_s_setprio(0);
        __builtin_amdgcn_s_barrier();

        // ---------------- phase 1 (fm=1) ----------------
        i32x8 a1 = ldfrag(cur, 0, wr * 128 + 32 + l31);
        __builtin_amdgcn_s_barrier();
        asm volatile("s_waitcnt lgkmcnt(0)" ::: "memory");
        __builtin_amdgcn_sched_barrier(0);
        __builtin_amdgcn_s_setprio(1);
        acc[1][0] = __builtin_amdgcn_mfma_scale_f32_32x32x64_f8f6f4(
            a1, b0, acc[1][0], 0, 0, 0, 0x7F7F7F7F, 0, 0x7F7F7F7F);
        acc[1][1] = __builtin_amdgcn_mfma_scale_f32_32x32x64_f8f6f4(
            a1, b1, acc[1][1], 0, 0, 0, 0x7F7F7F7F, 0, 0x7F7F7F7F);
        __builtin_amdgcn_s_setprio(0);
        __builtin_amdgcn_s_barrier();

        // ---------------- phase 2 (fm=2; stage half 1 of t+2) ------------
        i32x8 a2 = ldfrag(cur, 0, wr * 128 + 64 + l31);
        if (t + 2 < nt) stageH(fut, (t + 2) * 64, 1);
        __builtin_amdgcn_s_barrier();
        asm volatile("s_waitcnt lgkmcnt(0)" ::: "memory");
        __builtin_amdgcn_sched_barrier(0);
        __builtin_amdgcn_s_setprio(1);
        acc[2][0] = __builtin_amdgcn_mfma_scale_f32_32x32x64_f8f6f4(
            a2, b0, acc[2][0], 0, 0, 0, 0x7F7F7F7F, 0, 0x7F7F7F7F);
        acc[2][1] = __builtin_amdgcn_mfma_scale_f32_32x32x64_f8f6f4(
            a2, b1, acc[2][1], 0, 0, 0, 0x7F7F7F7F, 0, 0x7F7F7F7F);
        __builtin_amdgcn_s_setprio(0);
        __builtin_amdgcn_s_barrier();

        // ---------------- phase 3 (fm=3; counted vmcnt) -------------------
        i32x8 a3 = ldfrag(cur, 0, wr * 128 + 96 + l31);
        __builtin_amdgcn_s_barrier();
        asm volatile("s_waitcnt lgkmcnt(0)" ::: "memory");
        __builtin_amdgcn_sched_barrier(0);
        __builtin_amdgcn_s_setprio(1);
        acc[3][0] = __builtin_amdgcn_mfma_scale_f32_32x32x64_f8f6f4(
            a3, b0, acc[3][0], 0, 0, 0, 0x7F7F7F7F, 0, 0x7F7F7F7F);
        acc[3][1] = __builtin_amdgcn_mfma_scale_f32_32x32x64_f8f6f4(
            a3, b1, acc[3][1], 0, 0, 0, 0x7F7F7F7F, 0, 0x7F7F7F7F);
        __builtin_amdgcn_s_setprio(0);
        if (t + 1 < nt) {
            if (t + 2 < nt) {
                asm volatile("s_waitcnt vmcnt(4)" ::: "memory");  // t+1 landed
            } else {
                asm volatile("s_waitcnt vmcnt(0)" ::: "memory");
            }
            __builtin_amdgcn_s_barrier();
        }

        cur = (cur == 2) ? 0 : cur + 1;
    }

    // ---- epilogue: top-2 per (row, this wave's 64 cols) ----
    // 32x32 C/D: col = lane&31, row = (j&3) + 8*(j>>2) + 4*(lane>>5)
    const int nblk = V >> 8;
    const int blkn = bn >> 8;
#pragma unroll
    for (int fm = 0; fm < 4; ++fm)
#pragma unroll
        for (int j = 0; j < 16; ++j) {
            const int row = bm + wr * 128 + fm * 32 + (j & 3) + 8 * (j >> 2) + 4 * hl;
            const int c0 = bn + wc * 64 + l31;
            unsigned long long p0 =
                ((unsigned long long)fkey(acc[fm][0][j]) << 32) |
                (unsigned long long)(0xFFFFFFFFu - (unsigned int)c0);
            unsigned long long p1 =
                ((unsigned long long)fkey(acc[fm][1][j]) << 32) |
                (unsigned long long)(0xFFFFFFFFu - (unsigned int)(c0 + 32));
            unsigned long long t1 = p0 > p1 ? p0 : p1;
            unsigned long long t2 = p0 > p1 ? p1 : p0;
#pragma unroll
            for (int m = 1; m < 32; m <<= 1) {
                unsigned long long o1 = __shfl_xor(t1, m);
                unsigned long long o2 = __shfl_xor(t2, m);
                unsigned long long n1 = t1 > o1 ? t1 : o1;
                unsigned long long lo = t1 > o1 ? o1 : t1;
                unsigned long long m2 = t2 > o2 ? t2 : o2;
                t2 = lo > m2 ? lo : m2;
                t1 = n1;
            }
            if (l31 == 0) {   // lanes 0 and 32 (different rows)
                size_t ci = (((size_t)row * nblk + blkn) * 4 + wc) * 2;
                cand[ci] = t1;
                cand[ci + 1] = t2;
            }
        }
}

// ============================================================
// Refine (unchanged): one wave per row, Delta = 16.5.
// ============================================================
#define DELTA 16.5f

__global__ __launch_bounds__(256) void refine_kernel(
    const unsigned long long* __restrict__ cand,
    const float* __restrict__ X,
    const _Float16* __restrict__ DhT, const _Float16* __restrict__ DlT,
    float* __restrict__ out, int N, int D, int V)
{
    const int w = threadIdx.x >> 6, lane = threadIdx.x & 63;
    const int r = blockIdx.x * 4 + w;
    if (r >= N) return;

    const int nent = 256;                   // 256 entries per row
    const unsigned long long* cr = cand + (size_t)r * nent;

    unsigned long long p[4];
#pragma unroll
    for (int i = 0; i < 4; ++i) p[i] = cr[lane * 4 + i];

    unsigned long long pmax = p[0];
#pragma unroll
    for (int i = 1; i < 4; ++i) if (p[i] > pmax) pmax = p[i];
#pragma unroll
    for (int m = 1; m < 64; m <<= 1) {
        unsigned long long o = __shfl_xor(pmax, m);
        if (o > pmax) pmax = o;
    }

    const float s1 = unkey((unsigned int)(pmax >> 32));
    const unsigned int kthr = fkey(s1 - DELTA);

    int cnt = 0;
    unsigned long long masks[4];
#pragma unroll
    for (int i = 0; i < 4; ++i) {
        masks[i] = __ballot((unsigned int)(p[i] >> 32) >= kthr);
        cnt += __popcll(masks[i]);
    }

    if (cnt <= 1) {
        if (lane == 0)
            out[r] = (float)(0xFFFFFFFFu - (unsigned int)(pmax & 0xFFFFFFFFull));
        return;
    }

    const float* xrow = X + (size_t)r * D;
    float xbuf[32];
#pragma unroll
    for (int q = 0; q < 8; ++q) {
        float4 xv = *(const float4*)(xrow + lane * 32 + q * 4);
        xbuf[q * 4 + 0] = xv.x; xbuf[q * 4 + 1] = xv.y;
        xbuf[q * 4 + 2] = xv.z; xbuf[q * 4 + 3] = xv.w;
    }

    unsigned long long bestp = 0;
    for (int i = 0; i < 4; ++i) {
        unsigned long long mask = masks[i];
        while (mask) {
            const int src = __ffsll((unsigned long long)mask) - 1;
            mask &= mask - 1;
            const unsigned long long cp = __shfl(p[i], src);
            const int col = (int)(0xFFFFFFFFu - (unsigned int)(cp & 0xFFFFFFFFull));

            const f16x8* dh = (const f16x8*)(DhT + (size_t)col * D) + lane * 4;
            const f16x8* dl = (const f16x8*)(DlT + (size_t)col * D) + lane * 4;
            float s = 0.0f;
#pragma unroll
            for (int q = 0; q < 4; ++q) {
                f16x8 h = dh[q], l = dl[q];
#pragma unroll
                for (int e = 0; e < 8; ++e)
                    s = fmaf(xbuf[q * 8 + e], (float)h[e] + (float)l[e], s);
            }
#pragma unroll
            for (int m = 1; m < 64; m <<= 1) s += __shfl_xor(s, m);

            const unsigned long long pp =
                ((unsigned long long)fkey(s) << 32) |
                (unsigned long long)(0xFFFFFFFFu - (unsigned int)col);
            if (pp > bestp) bestp = pp;
        }
    }
    if (lane == 0)
        out[r] = (float)(0xFFFFFFFFu - (unsigned int)(bestp & 0xFFFFFFFFull));
}

// ============================================================
// Last-resort fallback: fp32 VALU kernel (round 1, known-passing).
// ============================================================
#define FBK 16
#define FTM 8
#define FTN 8

__global__ __launch_bounds__(256) void gemm_argmax_fp32_kernel(
    const float* __restrict__ A, const float* __restrict__ B,
    unsigned long long* __restrict__ best, int N, int D, int V)
{
    __shared__ float As[FBK][128 + 4];
    __shared__ float Bs[FBK][128 + 4];

    const int tid = threadIdx.x;
    const int tx = tid & 15;
    const int ty = tid >> 4;
    const int bm = blockIdx.y * 128;
    const int bn = blockIdx.x * 128;

    const int arow  = tid >> 2;
    const int acol4 = tid & 3;
    const int brow  = tid >> 5;
    const int bcol4 = tid & 31;

    float acc[FTM][FTN];
#pragma unroll
    for (int i = 0; i < FTM; ++i)
#pragma unroll
        for (int j = 0; j < FTN; ++j) acc[i][j] = 0.0f;

    for (int k0 = 0; k0 < D; k0 += FBK) {
        float4 a0 = *reinterpret_cast<const float4*>(&A[(size_t)(bm + arow) * D + k0 + acol4 * 4]);
        float4 a1 = *reinterpret_cast<const float4*>(&A[(size_t)(bm + arow + 64) * D + k0 + acol4 * 4]);
        float4 b0 = *reinterpret_cast<const float4*>(&B[(size_t)(k0 + brow) * V + bn + bcol4 * 4]);
        float4 b1 = *reinterpret_cast<const float4*>(&B[(size_t)(k0 + brow + 8) * V + bn + bcol4 * 4]);

        As[acol4 * 4 + 0][arow] = a0.x;
        As[acol4 * 4 + 1][arow] = a0.y;
        As[acol4 * 4 + 2][arow] = a0.z;
        As[acol4 * 4 + 3][arow] = a0.w;
        As[acol4 * 4 + 0][arow + 64] = a1.x;
        As[acol4 * 4 + 1][arow + 64] = a1.y;
        As[acol4 * 4 + 2][arow + 64] = a1.z;
        As[acol4 * 4 + 3][arow + 64] = a1.w;
        *reinterpret_cast<float4*>(&Bs[brow][bcol4 * 4]) = b0;
        *reinterpret_cast<float4*>(&Bs[brow + 8][bcol4 * 4]) = b1;

        __syncthreads();
#pragma unroll
        for (int kk = 0; kk < FBK; ++kk) {
            float4 av0 = *reinterpret_cast<const float4*>(&As[kk][ty * FTM]);
            float4 av1 = *reinterpret_cast<const float4*>(&As[kk][ty * FTM + 4]);
            float4 bv0 = *reinterpret_cast<const float4*>(&Bs[kk][tx * FTN]);
            float4 bv1 = *reinterpret_cast<const float4*>(&Bs[kk][tx * FTN + 4]);
            float a[FTM] = {av0.x, av0.y, av0.z, av0.w, av1.x, av1.y, av1.z, av1.w};
            float b[FTN] = {bv0.x, bv0.y, bv0.z, bv0.w, bv1.x, bv1.y, bv1.z, bv1.w};
#pragma unroll
            for (int i = 0; i < FTM; ++i)
#pragma unroll
                for (int j = 0; j < FTN; ++j)
                    acc[i][j] = fmaf(a[i], b[j], acc[i][j]);
        }
        __syncthreads();
    }

#pragma unroll
    for (int i = 0; i < FTM; ++i) {
        float bv = acc[i][0];
        int bc = bn + tx * FTN;
#pragma unroll
        for (int j = 1; j < FTN; ++j) {
            float v = acc[i][j];
            int c = bn + tx * FTN + j;
            if (v > bv) { bv = v; bc = c; }
        }
        unsigned long long packed =
            ((unsigned long long)fkey(bv) << 32) |
            (unsigned long long)(0xFFFFFFFFu - (unsigned int)bc);
#pragma unroll
        for (int m = 1; m < 16; m <<= 1) {
            unsigned long long o = __shfl_xor(packed, m, 16);
            if (o > packed) packed = o;
        }
        if (tx == 0) atomicMax(&best[bm + ty * FTM + i], packed);
    }
}

__global__ void decode_kernel(const unsigned long long* __restrict__ best,
                              float* __restrict__ out, int N)
{
    int i = blockIdx.x * blockDim.x + threadIdx.x;
    if (i < N) {
        unsigned int inv = (unsigned int)(best[i] & 0xFFFFFFFFull);
        out[i] = (float)(0xFFFFFFFFu - inv);
    }
}

extern "C" void kernel_launch(void* const* d_in, const int* in_sizes, int n_in,
                              void* d_out, int out_size, void* d_ws, size_t ws_size,
                              hipStream_t stream) {
    const float* A = (const float*)d_in[0];   // x  [N, D]
    const float* B = (const float*)d_in[1];   // di [D, V]
    float* out = (float*)d_out;

    const int N = out_size;                   // 16384
    const int D = in_sizes[0] / N;            // 2048
    const int V = in_sizes[1] / D;            // 8192

    const size_t szXq = (size_t)N * D;                       // 32 MB fp8
    const size_t szDq = (size_t)D * V;                       // 16 MB fp8
    const size_t szDh = (size_t)D * V * sizeof(_Float16);    // 32 MB
    const size_t candsz = (size_t)N * 256 * 8;               // 32 MB
    const size_t need = szXq + szDq + 2 * szDh + candsz;     // ~146 MB

    if (ws_size >= need) {
        char* wsp = (char*)d_ws;
        unsigned char* Xq  = (unsigned char*)(wsp);
        unsigned char* DqT = (unsigned char*)(wsp + szXq);
        _Float16* DhT = (_Float16*)(wsp + szXq + szDq);
        _Float16* DlT = (_Float16*)(wsp + szXq + szDq + szDh);
        unsigned long long* cand =
            (unsigned long long*)(wsp + szXq + szDq + 2 * szDh);

        static int attr_done = 0;   // host-side, idempotent
        if (!attr_done) {
            hipFuncSetAttribute((const void*)gemm_mx_top2,
                                hipFuncAttributeMaxDynamicSharedMemorySize, 98304);
            attr_done = 1;
        }

        prep_x_q<<<(int)(((size_t)N * D) / (256 * 8)), 256, 0, stream>>>(A, Xq);
        prep_di_q<<<dim3(V / 64, D / 32), 256, 0, stream>>>(B, DqT, DhT, DlT, D, V);
        gemm_mx_top2<<<(N / 256) * (V / 256), 512, 98304, stream>>>(
            Xq, DqT, cand, N, D, V);
        refine_kernel<<<(N + 3) / 4, 256, 0, stream>>>(
            cand, A, DhT, DlT, out, N, D, V);
    } else {
        unsigned long long* best = (unsigned long long*)d_ws;
        hipMemsetAsync(best, 0, (size_t)N * sizeof(unsigned long long), stream);
        gemm_argmax_fp32_kernel<<<dim3(V / 128, N / 128), 256, 0, stream>>>(A, B, best, N, D, V);
        decode_kernel<<<(N + 255) / 256, 256, 0, stream>>>(best, out, N);
    }
}

// Round 14
// 676.496 us; speedup vs baseline: 1.1087x; 1.1087x over previous
//
#include <hip/hip_runtime.h>

typedef _Float16 f16x8 __attribute__((ext_vector_type(8)));
typedef float f32x4 __attribute__((ext_vector_type(4)));
typedef float f32x16 __attribute__((ext_vector_type(16)));
typedef int i32x4 __attribute__((ext_vector_type(4)));
typedef int i32x8 __attribute__((ext_vector_type(8)));

__device__ __forceinline__ unsigned int fkey(float f) {
    unsigned int u = __float_as_uint(f);
    return u ^ ((u & 0x80000000u) ? 0xFFFFFFFFu : 0x80000000u);
}
__device__ __forceinline__ float unkey(unsigned int k) {
    unsigned int u = (k & 0x80000000u) ? (k ^ 0x80000000u) : ~k;
    return __uint_as_float(u);
}

// OCP e4m3fn encode, round-to-nearest-even (manual; known-good)
__device__ __forceinline__ unsigned int f32_to_e4m3(float f) {
    float a = fabsf(f);
    a = fminf(a, 448.0f);
    unsigned int s = (__float_as_uint(f) >> 24) & 0x80u;
    if (a < 0.015625f) {
        int m = (int)rintf(a * 512.0f);
        return s | (unsigned int)m;
    }
    int e = ilogbf(a);
    float step = ldexpf(1.0f, e - 3);
    int q = (int)rintf(a / step);
    if (q == 16) { e += 1; q = 8; }
    return s | (unsigned int)(((e + 7) << 3) | (q - 8));
}

// ============================================================
// Prep kernels (unchanged, known-good)
// ============================================================
__global__ __launch_bounds__(256) void prep_x_q(
    const float* __restrict__ x, unsigned char* __restrict__ Xq)
{
    size_t base = ((size_t)blockIdx.x * 256 + threadIdx.x) * 8;
    float4 a0 = *(const float4*)(x + base);
    float4 a1 = *(const float4*)(x + base + 4);
    float v[8] = {a0.x, a0.y, a0.z, a0.w, a1.x, a1.y, a1.z, a1.w};
    unsigned long long b = 0;
#pragma unroll
    for (int j = 0; j < 8; ++j)
        b |= (unsigned long long)f32_to_e4m3(v[j]) << (8 * j);
    *(unsigned long long*)(Xq + base) = b;
}

__global__ __launch_bounds__(256) void prep_di_q(
    const float* __restrict__ di, unsigned char* __restrict__ DqT,
    _Float16* __restrict__ DhT, _Float16* __restrict__ DlT, int D, int V)
{
    int v  = blockIdx.x * 64 + (threadIdx.x & 63);
    int d0 = blockIdx.y * 32 + (threadIdx.x >> 6) * 8;
    f16x8 h, l;
    unsigned long long b = 0;
#pragma unroll
    for (int j = 0; j < 8; ++j) {
        float val = di[(size_t)(d0 + j) * V + v];
        _Float16 hh = (_Float16)val;
        h[j] = hh;
        l[j] = (_Float16)(val - (float)hh);
        b |= (unsigned long long)f32_to_e4m3(val) << (8 * j);
    }
    *(unsigned long long*)(DqT + (size_t)v * D + d0) = b;
    *(f16x8*)(DhT + (size_t)v * D + d0) = h;
    *(f16x8*)(DlT + (size_t)v * D + d0) = l;
}

// ============================================================
// Fast pass: MX-scaled fp8 GEMM (unit scales), 128x128 tile, BK=64,
// 256 threads = 4 waves (2x2), per-wave 64x64 = 2x2 frags of 32x32
// (r12 geometry, absmax-0-verified). NEW this round:
//  (a) all per-lane ds_read byte-offsets precomputed pre-loop
//      (r12 recomputed swizzle math every tile -> 40% VALUBusy);
//  (b) TRIPLE-buffered LDS (3 x 16KB) + counted vmcnt: stage t+2,
//      s_waitcnt vmcnt(8) (tile t landed; t+1/t+2 stay in flight
//      ACROSS the barrier), raw s_barrier, compute, lgkmcnt(0),
//      s_barrier. Never vmcnt(0) in the main loop (m218 mechanism;
//      r12's __syncthreads drained vmcnt(0) every tile).
// 48KB LDS + (256,3) -> 3 blocks/CU = 12 waves/CU.
// ============================================================
__global__ __launch_bounds__(256, 3) void gemm_mx_top2(
    const unsigned char* __restrict__ Xq, const unsigned char* __restrict__ DqT,
    unsigned long long* __restrict__ cand, int N, int D, int V)
{
    __shared__ __align__(16) unsigned char sm[49152];   // 3 x (A 8KB | B 8KB)

    const int tid = threadIdx.x;
    const int w = tid >> 6, lane = tid & 63;
    const int wr = w >> 1, wc = w & 1;           // 2x2 wave grid
    const int l31 = lane & 31, hl = lane >> 5;

    // bijective XCD swizzle (8192 blocks % 8 == 0)
    const int cpx = gridDim.x >> 3;
    const int swz = (blockIdx.x & 7) * cpx + (blockIdx.x >> 3);
    const int bm = (swz >> 6) * 128;             // 128 m-tiles
    const int bn = (swz & 63) * 128;             // 64 n-tiles

    // staging: 16 chunks/buffer (A:0-7, B:8-15), chunk = 16 rows x 64B.
    // lane l -> row cc*16 + (l>>2), phys 16B slot l&3; source reads logical
    // slot sp ^ ((row>>1)&3) (pre-swizzle; matching XOR on ds_read).
    const int srow_in = lane >> 2;
    const int sp      = lane & 3;

    const unsigned char* srcbase[4];
    int dstoff[4];
#pragma unroll
    for (int i = 0; i < 4; ++i) {
        const int c = w * 4 + i;                 // 0..15
        const int isB = (c >= 8);
        const int cc = isB ? c - 8 : c;
        const int row = cc * 16 + srow_in;
        const int slog = sp ^ ((row >> 1) & 3);
        srcbase[i] = (isB ? DqT + (size_t)(bn + row) * D
                          : Xq + (size_t)(bm + row) * D) + slog * 16;
        dstoff[i] = (isB ? 8192 : 0) + cc * 1024;
    }

    auto stage = [&](int buf, int k0) {
#pragma unroll
        for (int i = 0; i < 4; ++i) {
            __builtin_amdgcn_global_load_lds(
                (const __attribute__((address_space(1))) void*)(srcbase[i] + k0),
                (__attribute__((address_space(3))) void*)
                    (sm + buf * 16384 + dstoff[i]),
                16, 0, 0);
        }
    };

    // (a) precompute the 8 ds_read byte-offsets (within one buffer).
    // frag f reads op/row: f0: B row wc*64+l31; f1: B row wc*64+32+l31;
    //                      f2: A row wr*64+l31; f3: A row wr*64+32+l31.
    int rdlo[4], rdhi[4];
#pragma unroll
    for (int f = 0; f < 4; ++f) {
        const int op = (f < 2) ? 1 : 0;
        const int r  = (op ? wc : wr) * 64 + (f & 1) * 32 + l31;
        const int base = (op ? 8192 : 0) + (r >> 4) * 1024 + (r & 15) * 64;
        const int sw = (r >> 1) & 3;
        rdlo[f] = base + (((hl << 1)    ) ^ sw) * 16;
        rdhi[f] = base + (((hl << 1) | 1) ^ sw) * 16;
    }
    auto ldfrag = [&](int bufbase, int f) -> i32x8 {
        i32x4 lo = *(const i32x4*)(sm + bufbase + rdlo[f]);
        i32x4 hi = *(const i32x4*)(sm + bufbase + rdhi[f]);
        return __builtin_shufflevector(lo, hi, 0, 1, 2, 3, 4, 5, 6, 7);
    };

    f32x16 acc[2][2];
#pragma unroll
    for (int fm = 0; fm < 2; ++fm)
#pragma unroll
        for (int fn = 0; fn < 2; ++fn)
#pragma unroll
            for (int q = 0; q < 16; ++q) acc[fm][fn][q] = 0.0f;

    const int nt = D / 64;   // 32
    int cb = 0;              // buffer of tile t
    int sb = 2;              // buffer for tile t+2

    // prologue: tiles 0,1 staged (8 loads/wave outstanding)
    stage(0, 0);
    stage(1, 64);
    asm volatile("s_waitcnt vmcnt(4)" ::: "memory");   // tile 0 landed
    __builtin_amdgcn_s_barrier();

#pragma unroll 1
    for (int t = 0; t < nt; ++t) {
        if (t + 2 < nt) {
            stage(sb, (t + 2) * 64);                       // 12 outstanding
            asm volatile("s_waitcnt vmcnt(8)" ::: "memory");   // t landed
        } else if (t + 1 < nt) {
            asm volatile("s_waitcnt vmcnt(4)" ::: "memory");   // t landed
        } else {
            asm volatile("s_waitcnt vmcnt(0)" ::: "memory");
        }
        __builtin_amdgcn_s_barrier();   // tile t visible to all waves

        const int bufbase = cb * 16384;
        i32x8 b0 = ldfrag(bufbase, 0);
        i32x8 b1 = ldfrag(bufbase, 1);
        i32x8 a0 = ldfrag(bufbase, 2);
        i32x8 a1 = ldfrag(bufbase, 3);
        acc[0][0] = __builtin_amdgcn_mfma_scale_f32_32x32x64_f8f6f4(
            a0, b0, acc[0][0], 0, 0, 0, 0x7F7F7F7F, 0, 0x7F7F7F7F);
        acc[0][1] = __builtin_amdgcn_mfma_scale_f32_32x32x64_f8f6f4(
            a0, b1, acc[0][1], 0, 0, 0, 0x7F7F7F7F, 0, 0x7F7F7F7F);
        acc[1][0] = __builtin_amdgcn_mfma_scale_f32_32x32x64_f8f6f4(
            a1, b0, acc[1][0], 0, 0, 0, 0x7F7F7F7F, 0, 0x7F7F7F7F);
        acc[1][1] = __builtin_amdgcn_mfma_scale_f32_32x32x64_f8f6f4(
            a1, b1, acc[1][1], 0, 0, 0, 0x7F7F7F7F, 0, 0x7F7F7F7F);

        // reads of buf cb done before anyone re-stages it (t+... mod 3)
        asm volatile("s_waitcnt lgkmcnt(0)" ::: "memory");
        __builtin_amdgcn_s_barrier();

        cb = (cb == 2) ? 0 : cb + 1;
        sb = (sb == 2) ? 0 : sb + 1;
    }

    // ---- epilogue: top-2 per (row, this wave's 64 cols) ----
    // 32x32 C/D: col = lane&31, row = (j&3) + 8*(j>>2) + 4*(lane>>5)
#pragma unroll
    for (int fm = 0; fm < 2; ++fm)
#pragma unroll
        for (int j = 0; j < 16; ++j) {
            const int row = bm + wr * 64 + fm * 32 + (j & 3) + 8 * (j >> 2) + 4 * hl;
            const int c0 = bn + wc * 64 + l31;
            unsigned long long p0 =
                ((unsigned long long)fkey(acc[fm][0][j]) << 32) |
                (unsigned long long)(0xFFFFFFFFu - (unsigned int)c0);
            unsigned long long p1 =
                ((unsigned long long)fkey(acc[fm][1][j]) << 32) |
                (unsigned long long)(0xFFFFFFFFu - (unsigned int)(c0 + 32));
            unsigned long long t1 = p0 > p1 ? p0 : p1;
            unsigned long long t2 = p0 > p1 ? p1 : p0;
#pragma unroll
            for (int m = 1; m < 32; m <<= 1) {
                unsigned long long o1 = __shfl_xor(t1, m);
                unsigned long long o2 = __shfl_xor(t2, m);
                unsigned long long n1 = t1 > o1 ? t1 : o1;
                unsigned long long lo = t1 > o1 ? o1 : t1;
                unsigned long long m2 = t2 > o2 ? t2 : o2;
                t2 = lo > m2 ? lo : m2;
                t1 = n1;
            }
            if (l31 == 0) {   // lanes 0 and 32 (different rows)
                size_t ci = ((size_t)row * 128 + (bn >> 6) + wc) * 2;
                cand[ci] = t1;
                cand[ci + 1] = t2;
            }
        }
}

// ============================================================
// Refine (unchanged): one wave per row, Delta = 16.5.
// ============================================================
#define DELTA 16.5f

__global__ __launch_bounds__(256) void refine_kernel(
    const unsigned long long* __restrict__ cand,
    const float* __restrict__ X,
    const _Float16* __restrict__ DhT, const _Float16* __restrict__ DlT,
    float* __restrict__ out, int N, int D, int V)
{
    const int w = threadIdx.x >> 6, lane = threadIdx.x & 63;
    const int r = blockIdx.x * 4 + w;
    if (r >= N) return;

    const int nent = 256;                   // 256 entries per row
    const unsigned long long* cr = cand + (size_t)r * nent;

    unsigned long long p[4];
#pragma unroll
    for (int i = 0; i < 4; ++i) p[i] = cr[lane * 4 + i];

    unsigned long long pmax = p[0];
#pragma unroll
    for (int i = 1; i < 4; ++i) if (p[i] > pmax) pmax = p[i];
#pragma unroll
    for (int m = 1; m < 64; m <<= 1) {
        unsigned long long o = __shfl_xor(pmax, m);
        if (o > pmax) pmax = o;
    }

    const float s1 = unkey((unsigned int)(pmax >> 32));
    const unsigned int kthr = fkey(s1 - DELTA);

    int cnt = 0;
    unsigned long long masks[4];
#pragma unroll
    for (int i = 0; i < 4; ++i) {
        masks[i] = __ballot((unsigned int)(p[i] >> 32) >= kthr);
        cnt += __popcll(masks[i]);
    }

    if (cnt <= 1) {
        if (lane == 0)
            out[r] = (float)(0xFFFFFFFFu - (unsigned int)(pmax & 0xFFFFFFFFull));
        return;
    }

    const float* xrow = X + (size_t)r * D;
    float xbuf[32];
#pragma unroll
    for (int q = 0; q < 8; ++q) {
        float4 xv = *(const float4*)(xrow + lane * 32 + q * 4);
        xbuf[q * 4 + 0] = xv.x; xbuf[q * 4 + 1] = xv.y;
        xbuf[q * 4 + 2] = xv.z; xbuf[q * 4 + 3] = xv.w;
    }

    unsigned long long bestp = 0;
    for (int i = 0; i < 4; ++i) {
        unsigned long long mask = masks[i];
        while (mask) {
            const int src = __ffsll((unsigned long long)mask) - 1;
            mask &= mask - 1;
            const unsigned long long cp = __shfl(p[i], src);
            const int col = (int)(0xFFFFFFFFu - (unsigned int)(cp & 0xFFFFFFFFull));

            const f16x8* dh = (const f16x8*)(DhT + (size_t)col * D) + lane * 4;
            const f16x8* dl = (const f16x8*)(DlT + (size_t)col * D) + lane * 4;
            float s = 0.0f;
#pragma unroll
            for (int q = 0; q < 4; ++q) {
                f16x8 h = dh[q], l = dl[q];
#pragma unroll
                for (int e = 0; e < 8; ++e)
                    s = fmaf(xbuf[q * 8 + e], (float)h[e] + (float)l[e], s);
            }
#pragma unroll
            for (int m = 1; m < 64; m <<= 1) s += __shfl_xor(s, m);

            const unsigned long long pp =
                ((unsigned long long)fkey(s) << 32) |
                (unsigned long long)(0xFFFFFFFFu - (unsigned int)col);
            if (pp > bestp) bestp = pp;
        }
    }
    if (lane == 0)
        out[r] = (float)(0xFFFFFFFFu - (unsigned int)(bestp & 0xFFFFFFFFull));
}

// ============================================================
// Last-resort fallback: fp32 VALU kernel (round 1, known-passing).
// ============================================================
#define FBK 16
#define FTM 8
#define FTN 8

__global__ __launch_bounds__(256) void gemm_argmax_fp32_kernel(
    const float* __restrict__ A, const float* __restrict__ B,
    unsigned long long* __restrict__ best, int N, int D, int V)
{
    __shared__ float As[FBK][128 + 4];
    __shared__ float Bs[FBK][128 + 4];

    const int tid = threadIdx.x;
    const int tx = tid & 15;
    const int ty = tid >> 4;
    const int bm = blockIdx.y * 128;
    const int bn = blockIdx.x * 128;

    const int arow  = tid >> 2;
    const int acol4 = tid & 3;
    const int brow  = tid >> 5;
    const int bcol4 = tid & 31;

    float acc[FTM][FTN];
#pragma unroll
    for (int i = 0; i < FTM; ++i)
#pragma unroll
        for (int j = 0; j < FTN; ++j) acc[i][j] = 0.0f;

    for (int k0 = 0; k0 < D; k0 += FBK) {
        float4 a0 = *reinterpret_cast<const float4*>(&A[(size_t)(bm + arow) * D + k0 + acol4 * 4]);
        float4 a1 = *reinterpret_cast<const float4*>(&A[(size_t)(bm + arow + 64) * D + k0 + acol4 * 4]);
        float4 b0 = *reinterpret_cast<const float4*>(&B[(size_t)(k0 + brow) * V + bn + bcol4 * 4]);
        float4 b1 = *reinterpret_cast<const float4*>(&B[(size_t)(k0 + brow + 8) * V + bn + bcol4 * 4]);

        As[acol4 * 4 + 0][arow] = a0.x;
        As[acol4 * 4 + 1][arow] = a0.y;
        As[acol4 * 4 + 2][arow] = a0.z;
        As[acol4 * 4 + 3][arow] = a0.w;
        As[acol4 * 4 + 0][arow + 64] = a1.x;
        As[acol4 * 4 + 1][arow + 64] = a1.y;
        As[acol4 * 4 + 2][arow + 64] = a1.z;
        As[acol4 * 4 + 3][arow + 64] = a1.w;
        *reinterpret_cast<float4*>(&Bs[brow][bcol4 * 4]) = b0;
        *reinterpret_cast<float4*>(&Bs[brow + 8][bcol4 * 4]) = b1;

        __syncthreads();
#pragma unroll
        for (int kk = 0; kk < FBK; ++kk) {
            float4 av0 = *reinterpret_cast<const float4*>(&As[kk][ty * FTM]);
            float4 av1 = *reinterpret_cast<const float4*>(&As[kk][ty * FTM + 4]);
            float4 bv0 = *reinterpret_cast<const float4*>(&Bs[kk][tx * FTN]);
            float4 bv1 = *reinterpret_cast<const float4*>(&Bs[kk][tx * FTN + 4]);
            float a[FTM] = {av0.x, av0.y, av0.z, av0.w, av1.x, av1.y, av1.z, av1.w};
            float b[FTN] = {bv0.x, bv0.y, bv0.z, bv0.w, bv1.x, bv1.y, bv1.z, bv1.w};
#pragma unroll
            for (int i = 0; i < FTM; ++i)
#pragma unroll
                for (int j = 0; j < FTN; ++j)
                    acc[i][j] = fmaf(a[i], b[j], acc[i][j]);
        }
        __syncthreads();
    }

#pragma unroll
    for (int i = 0; i < FTM; ++i) {
        float bv = acc[i][0];
        int bc = bn + tx * FTN;
#pragma unroll
        for (int j = 1; j < FTN; ++j) {
            float v = acc[i][j];
            int c = bn + tx * FTN + j;
            if (v > bv) { bv = v; bc = c; }
        }
        unsigned long long packed =
            ((unsigned long long)fkey(bv) << 32) |
            (unsigned long long)(0xFFFFFFFFu - (unsigned int)bc);
#pragma unroll
        for (int m = 1; m < 16; m <<= 1) {
            unsigned long long o = __shfl_xor(packed, m, 16);
            if (o > packed) packed = o;
        }
        if (tx == 0) atomicMax(&best[bm + ty * FTM + i], packed);
    }
}

__global__ void decode_kernel(const unsigned long long* __restrict__ best,
                              float* __restrict__ out, int N)
{
    int i = blockIdx.x * blockDim.x + threadIdx.x;
    if (i < N) {
        unsigned int inv = (unsigned int)(best[i] & 0xFFFFFFFFull);
        out[i] = (float)(0xFFFFFFFFu - inv);
    }
}

extern "C" void kernel_launch(void* const* d_in, const int* in_sizes, int n_in,
                              void* d_out, int out_size, void* d_ws, size_t ws_size,
                              hipStream_t stream) {
    const float* A = (const float*)d_in[0];   // x  [N, D]
    const float* B = (const float*)d_in[1];   // di [D, V]
    float* out = (float*)d_out;

    const int N = out_size;                   // 16384
    const int D = in_sizes[0] / N;            // 2048
    const int V = in_sizes[1] / D;            // 8192

    const size_t szXq = (size_t)N * D;                       // 32 MB fp8
    const size_t szDq = (size_t)D * V;                       // 16 MB fp8
    const size_t szDh = (size_t)D * V * sizeof(_Float16);    // 32 MB
    const size_t candsz = (size_t)N * 256 * 8;               // 32 MB
    const size_t need = szXq + szDq + 2 * szDh + candsz;     // ~146 MB

    if (ws_size >= need) {
        char* wsp = (char*)d_ws;
        unsigned char* Xq  = (unsigned char*)(wsp);
        unsigned char* DqT = (unsigned char*)(wsp + szXq);
        _Float16* DhT = (_Float16*)(wsp + szXq + szDq);
        _Float16* DlT = (_Float16*)(wsp + szXq + szDq + szDh);
        unsigned long long* cand =
            (unsigned long long*)(wsp + szXq + szDq + 2 * szDh);

        prep_x_q<<<(int)(((size_t)N * D) / (256 * 8)), 256, 0, stream>>>(A, Xq);
        prep_di_q<<<dim3(V / 64, D / 32), 256, 0, stream>>>(B, DqT, DhT, DlT, D, V);
        gemm_mx_top2<<<(N / 128) * (V / 128), 256, 0, stream>>>(
            Xq, DqT, cand, N, D, V);
        refine_kernel<<<(N + 3) / 4, 256, 0, stream>>>(
            cand, A, DhT, DlT, out, N, D, V);
    } else {
        unsigned long long* best = (unsigned long long*)d_ws;
        hipMemsetAsync(best, 0, (size_t)N * sizeof(unsigned long long), stream);
        gemm_argmax_fp32_kernel<<<dim3(V / 128, N / 128), 256, 0, stream>>>(A, B, best, N, D, V);
        decode_kernel<<<(N + 255) / 256, 256, 0, stream>>>(best, out, N);
    }
}

// Round 15
// 617.031 us; speedup vs baseline: 1.2156x; 1.0964x over previous
//
#include <hip/hip_runtime.h>

typedef _Float16 f16x8 __attribute__((ext_vector_type(8)));
typedef float f32x4 __attribute__((ext_vector_type(4)));
typedef float f32x16 __attribute__((ext_vector_type(16)));
typedef int i32x4 __attribute__((ext_vector_type(4)));
typedef int i32x8 __attribute__((ext_vector_type(8)));

__device__ __forceinline__ unsigned int fkey(float f) {
    unsigned int u = __float_as_uint(f);
    return u ^ ((u & 0x80000000u) ? 0xFFFFFFFFu : 0x80000000u);
}
__device__ __forceinline__ float unkey(unsigned int k) {
    unsigned int u = (k & 0x80000000u) ? (k ^ 0x80000000u) : ~k;
    return __uint_as_float(u);
}

// OCP e4m3fn encode, round-to-nearest-even (manual; known-good)
__device__ __forceinline__ unsigned int f32_to_e4m3(float f) {
    float a = fabsf(f);
    a = fminf(a, 448.0f);
    unsigned int s = (__float_as_uint(f) >> 24) & 0x80u;
    if (a < 0.015625f) {
        int m = (int)rintf(a * 512.0f);
        return s | (unsigned int)m;
    }
    int e = ilogbf(a);
    float step = ldexpf(1.0f, e - 3);
    int q = (int)rintf(a / step);
    if (q == 16) { e += 1; q = 8; }
    return s | (unsigned int)(((e + 7) << 3) | (q - 8));
}

// ============================================================
// Prep kernels (unchanged, known-good)
// ============================================================
__global__ __launch_bounds__(256) void prep_x_q(
    const float* __restrict__ x, unsigned char* __restrict__ Xq)
{
    size_t base = ((size_t)blockIdx.x * 256 + threadIdx.x) * 8;
    float4 a0 = *(const float4*)(x + base);
    float4 a1 = *(const float4*)(x + base + 4);
    float v[8] = {a0.x, a0.y, a0.z, a0.w, a1.x, a1.y, a1.z, a1.w};
    unsigned long long b = 0;
#pragma unroll
    for (int j = 0; j < 8; ++j)
        b |= (unsigned long long)f32_to_e4m3(v[j]) << (8 * j);
    *(unsigned long long*)(Xq + base) = b;
}

__global__ __launch_bounds__(256) void prep_di_q(
    const float* __restrict__ di, unsigned char* __restrict__ DqT,
    _Float16* __restrict__ DhT, _Float16* __restrict__ DlT, int D, int V)
{
    int v  = blockIdx.x * 64 + (threadIdx.x & 63);
    int d0 = blockIdx.y * 32 + (threadIdx.x >> 6) * 8;
    f16x8 h, l;
    unsigned long long b = 0;
#pragma unroll
    for (int j = 0; j < 8; ++j) {
        float val = di[(size_t)(d0 + j) * V + v];
        _Float16 hh = (_Float16)val;
        h[j] = hh;
        l[j] = (_Float16)(val - (float)hh);
        b |= (unsigned long long)f32_to_e4m3(val) << (8 * j);
    }
    *(unsigned long long*)(DqT + (size_t)v * D + d0) = b;
    *(f16x8*)(DhT + (size_t)v * D + d0) = h;
    *(f16x8*)(DlT + (size_t)v * D + d0) = l;
}

// ============================================================
// Fast pass: MX-scaled fp8 GEMM (unit scales), 128x128 tile, BK=64,
// 256 threads = 4 waves (2x2), per-wave 64x64 = 2x2 frags of 32x32.
// EXACTLY the round-12 champion core (gemm 545us, absmax 0) except the
// block->tile mapping: 8x8-block SUPER-TILES (A-panels 8x256KB +
// B-panels 8x256KB = 4MB = one XCD L2), two super-rows per XCD.
// r12's map streamed 16MB of B per bm-sweep through a 4MB L2 ->
// FETCH 1.06GB (22x overfetch) and L3-latency staging; this map makes
// staging mostly L2-hits.
// ============================================================
__global__ __launch_bounds__(256, 4) void gemm_mx_top2(
    const unsigned char* __restrict__ Xq, const unsigned char* __restrict__ DqT,
    unsigned long long* __restrict__ cand, int N, int D, int V)
{
    __shared__ __align__(16) unsigned char sm[32768];   // 2 x (A 8KB | B 8KB)

    const int tid = threadIdx.x;
    const int w = tid >> 6, lane = tid & 63;
    const int wr = w >> 1, wc = w & 1;           // 2x2 wave grid
    const int l31 = lane & 31, hl = lane >> 5;

    // L2-locality bijective mapping (8192 blocks = 128 bm x 64 bn tiles):
    // xcd = bid&7 (dispatch heuristic), 16 super-tiles per XCD,
    // super-tile = 8x8 blocks, super-grid = 16 rows x 8 cols.
    const int xcd = blockIdx.x & 7;
    const int s   = blockIdx.x >> 3;             // 0..1023 within XCD
    const int sl  = xcd * 16 + (s >> 6);         // global super-tile 0..127
    const int in  = s & 63;                      // position within 8x8
    const int bm  = ((sl >> 3) * 8 + (in >> 3)) * 128;   // 128 bm-tiles
    const int bn  = ((sl & 7) * 8 + (in & 7)) * 128;     // 64 bn-tiles

    // staging: 16 chunks/buffer (A:0-7, B:8-15), chunk = 16 rows x 64B.
    // lane l -> row cc*16 + (l>>2), phys 16B slot l&3; source reads logical
    // slot sp ^ ((row>>1)&3) (pre-swizzle; matching XOR on ds_read).
    const int srow_in = lane >> 2;
    const int sp      = lane & 3;

    const unsigned char* srcbase[4];
    int dstoff[4];
#pragma unroll
    for (int i = 0; i < 4; ++i) {
        const int c = w * 4 + i;                 // 0..15
        const int isB = (c >= 8);
        const int cc = isB ? c - 8 : c;
        const int row = cc * 16 + srow_in;
        const int slog = sp ^ ((row >> 1) & 3);
        srcbase[i] = (isB ? DqT + (size_t)(bn + row) * D
                          : Xq + (size_t)(bm + row) * D) + slog * 16;
        dstoff[i] = (isB ? 8192 : 0) + cc * 1024;
    }

    auto stage = [&](int buf, int k0) {
#pragma unroll
        for (int i = 0; i < 4; ++i) {
            __builtin_amdgcn_global_load_lds(
                (const __attribute__((address_space(1))) void*)(srcbase[i] + k0),
                (__attribute__((address_space(3))) void*)
                    (sm + buf * 16384 + dstoff[i]),
                16, 0, 0);
        }
    };
    // frag read: operand op (0=A,1=B), tile-local row r, k-half hl -> 32B
    auto ldfrag = [&](int buf, int op, int r) -> i32x8 {
        const unsigned char* base =
            sm + buf * 16384 + (op ? 8192 : 0) + (r >> 4) * 1024 + (r & 15) * 64;
        const int sw = (r >> 1) & 3;
        i32x4 lo = *(const i32x4*)(base + (((hl << 1)    ) ^ sw) * 16);
        i32x4 hi = *(const i32x4*)(base + (((hl << 1) | 1) ^ sw) * 16);
        return __builtin_shufflevector(lo, hi, 0, 1, 2, 3, 4, 5, 6, 7);
    };

    f32x16 acc[2][2];
#pragma unroll
    for (int fm = 0; fm < 2; ++fm)
#pragma unroll
        for (int fn = 0; fn < 2; ++fn)
#pragma unroll
            for (int q = 0; q < 16; ++q) acc[fm][fn][q] = 0.0f;

    const int nt = D / 64;   // 32
    int cb = 0;

    stage(0, 0);
    __syncthreads();

#pragma unroll 1
    for (int t = 0; t < nt; ++t) {
        if (t + 1 < nt) stage(cb ^ 1, (t + 1) * 64);   // fire-and-forget

        i32x8 b0 = ldfrag(cb, 1, wc * 64 + l31);
        i32x8 b1 = ldfrag(cb, 1, wc * 64 + 32 + l31);
        i32x8 a0 = ldfrag(cb, 0, wr * 64 + l31);
        i32x8 a1 = ldfrag(cb, 0, wr * 64 + 32 + l31);
        acc[0][0] = __builtin_amdgcn_mfma_scale_f32_32x32x64_f8f6f4(
            a0, b0, acc[0][0], 0, 0, 0, 0x7F7F7F7F, 0, 0x7F7F7F7F);
        acc[0][1] = __builtin_amdgcn_mfma_scale_f32_32x32x64_f8f6f4(
            a0, b1, acc[0][1], 0, 0, 0, 0x7F7F7F7F, 0, 0x7F7F7F7F);
        acc[1][0] = __builtin_amdgcn_mfma_scale_f32_32x32x64_f8f6f4(
            a1, b0, acc[1][0], 0, 0, 0, 0x7F7F7F7F, 0, 0x7F7F7F7F);
        acc[1][1] = __builtin_amdgcn_mfma_scale_f32_32x32x64_f8f6f4(
            a1, b1, acc[1][1], 0, 0, 0, 0x7F7F7F7F, 0, 0x7F7F7F7F);

        __syncthreads();   // drains vmcnt(staging) + lgkm; one barrier/tile
        cb ^= 1;
    }

    // ---- epilogue: top-2 per (row, this wave's 64 cols) ----
    // 32x32 C/D: col = lane&31, row = (j&3) + 8*(j>>2) + 4*(lane>>5)
#pragma unroll
    for (int fm = 0; fm < 2; ++fm)
#pragma unroll
        for (int j = 0; j < 16; ++j) {
            const int row = bm + wr * 64 + fm * 32 + (j & 3) + 8 * (j >> 2) + 4 * hl;
            const int c0 = bn + wc * 64 + l31;
            unsigned long long p0 =
                ((unsigned long long)fkey(acc[fm][0][j]) << 32) |
                (unsigned long long)(0xFFFFFFFFu - (unsigned int)c0);
            unsigned long long p1 =
                ((unsigned long long)fkey(acc[fm][1][j]) << 32) |
                (unsigned long long)(0xFFFFFFFFu - (unsigned int)(c0 + 32));
            unsigned long long t1 = p0 > p1 ? p0 : p1;
            unsigned long long t2 = p0 > p1 ? p1 : p0;
#pragma unroll
            for (int m = 1; m < 32; m <<= 1) {
                unsigned long long o1 = __shfl_xor(t1, m);
                unsigned long long o2 = __shfl_xor(t2, m);
                unsigned long long n1 = t1 > o1 ? t1 : o1;
                unsigned long long lo = t1 > o1 ? o1 : t1;
                unsigned long long m2 = t2 > o2 ? t2 : o2;
                t2 = lo > m2 ? lo : m2;
                t1 = n1;
            }
            if (l31 == 0) {   // lanes 0 and 32 (different rows)
                size_t ci = ((size_t)row * 128 + (bn >> 6) + wc) * 2;
                cand[ci] = t1;
                cand[ci + 1] = t2;
            }
        }
}

// ============================================================
// Refine: one wave per row. DELTA = 10.0 (6.1 sigma of the fp8 score
// noise sigma~1.6) -> E[candidates] ~2.6/row vs 4.7 at 16.5, saving
// ~275MB of DhT/DlT traffic. Rescore qualifiers exactly.
// ============================================================
#define DELTA 10.0f

__global__ __launch_bounds__(256) void refine_kernel(
    const unsigned long long* __restrict__ cand,
    const float* __restrict__ X,
    const _Float16* __restrict__ DhT, const _Float16* __restrict__ DlT,
    float* __restrict__ out, int N, int D, int V)
{
    const int w = threadIdx.x >> 6, lane = threadIdx.x & 63;
    const int r = blockIdx.x * 4 + w;
    if (r >= N) return;

    const int nent = 256;                   // 256 entries per row
    const unsigned long long* cr = cand + (size_t)r * nent;

    unsigned long long p[4];
#pragma unroll
    for (int i = 0; i < 4; ++i) p[i] = cr[lane * 4 + i];

    unsigned long long pmax = p[0];
#pragma unroll
    for (int i = 1; i < 4; ++i) if (p[i] > pmax) pmax = p[i];
#pragma unroll
    for (int m = 1; m < 64; m <<= 1) {
        unsigned long long o = __shfl_xor(pmax, m);
        if (o > pmax) pmax = o;
    }

    const float s1 = unkey((unsigned int)(pmax >> 32));
    const unsigned int kthr = fkey(s1 - DELTA);

    int cnt = 0;
    unsigned long long masks[4];
#pragma unroll
    for (int i = 0; i < 4; ++i) {
        masks[i] = __ballot((unsigned int)(p[i] >> 32) >= kthr);
        cnt += __popcll(masks[i]);
    }

    if (cnt <= 1) {
        if (lane == 0)
            out[r] = (float)(0xFFFFFFFFu - (unsigned int)(pmax & 0xFFFFFFFFull));
        return;
    }

    const float* xrow = X + (size_t)r * D;
    float xbuf[32];
#pragma unroll
    for (int q = 0; q < 8; ++q) {
        float4 xv = *(const float4*)(xrow + lane * 32 + q * 4);
        xbuf[q * 4 + 0] = xv.x; xbuf[q * 4 + 1] = xv.y;
        xbuf[q * 4 + 2] = xv.z; xbuf[q * 4 + 3] = xv.w;
    }

    unsigned long long bestp = 0;
    for (int i = 0; i < 4; ++i) {
        unsigned long long mask = masks[i];
        while (mask) {
            const int src = __ffsll((unsigned long long)mask) - 1;
            mask &= mask - 1;
            const unsigned long long cp = __shfl(p[i], src);
            const int col = (int)(0xFFFFFFFFu - (unsigned int)(cp & 0xFFFFFFFFull));

            const f16x8* dh = (const f16x8*)(DhT + (size_t)col * D) + lane * 4;
            const f16x8* dl = (const f16x8*)(DlT + (size_t)col * D) + lane * 4;
            float s = 0.0f;
#pragma unroll
            for (int q = 0; q < 4; ++q) {
                f16x8 h = dh[q], l = dl[q];
#pragma unroll
                for (int e = 0; e < 8; ++e)
                    s = fmaf(xbuf[q * 8 + e], (float)h[e] + (float)l[e], s);
            }
#pragma unroll
            for (int m = 1; m < 64; m <<= 1) s += __shfl_xor(s, m);

            const unsigned long long pp =
                ((unsigned long long)fkey(s) << 32) |
                (unsigned long long)(0xFFFFFFFFu - (unsigned int)col);
            if (pp > bestp) bestp = pp;
        }
    }
    if (lane == 0)
        out[r] = (float)(0xFFFFFFFFu - (unsigned int)(bestp & 0xFFFFFFFFull));
}

// ============================================================
// Last-resort fallback: fp32 VALU kernel (round 1, known-passing).
// ============================================================
#define FBK 16
#define FTM 8
#define FTN 8

__global__ __launch_bounds__(256) void gemm_argmax_fp32_kernel(
    const float* __restrict__ A, const float* __restrict__ B,
    unsigned long long* __restrict__ best, int N, int D, int V)
{
    __shared__ float As[FBK][128 + 4];
    __shared__ float Bs[FBK][128 + 4];

    const int tid = threadIdx.x;
    const int tx = tid & 15;
    const int ty = tid >> 4;
    const int bm = blockIdx.y * 128;
    const int bn = blockIdx.x * 128;

    const int arow  = tid >> 2;
    const int acol4 = tid & 3;
    const int brow  = tid >> 5;
    const int bcol4 = tid & 31;

    float acc[FTM][FTN];
#pragma unroll
    for (int i = 0; i < FTM; ++i)
#pragma unroll
        for (int j = 0; j < FTN; ++j) acc[i][j] = 0.0f;

    for (int k0 = 0; k0 < D; k0 += FBK) {
        float4 a0 = *reinterpret_cast<const float4*>(&A[(size_t)(bm + arow) * D + k0 + acol4 * 4]);
        float4 a1 = *reinterpret_cast<const float4*>(&A[(size_t)(bm + arow + 64) * D + k0 + acol4 * 4]);
        float4 b0 = *reinterpret_cast<const float4*>(&B[(size_t)(k0 + brow) * V + bn + bcol4 * 4]);
        float4 b1 = *reinterpret_cast<const float4*>(&B[(size_t)(k0 + brow + 8) * V + bn + bcol4 * 4]);

        As[acol4 * 4 + 0][arow] = a0.x;
        As[acol4 * 4 + 1][arow] = a0.y;
        As[acol4 * 4 + 2][arow] = a0.z;
        As[acol4 * 4 + 3][arow] = a0.w;
        As[acol4 * 4 + 0][arow + 64] = a1.x;
        As[acol4 * 4 + 1][arow + 64] = a1.y;
        As[acol4 * 4 + 2][arow + 64] = a1.z;
        As[acol4 * 4 + 3][arow + 64] = a1.w;
        *reinterpret_cast<float4*>(&Bs[brow][bcol4 * 4]) = b0;
        *reinterpret_cast<float4*>(&Bs[brow + 8][bcol4 * 4]) = b1;

        __syncthreads();
#pragma unroll
        for (int kk = 0; kk < FBK; ++kk) {
            float4 av0 = *reinterpret_cast<const float4*>(&As[kk][ty * FTM]);
            float4 av1 = *reinterpret_cast<const float4*>(&As[kk][ty * FTM + 4]);
            float4 bv0 = *reinterpret_cast<const float4*>(&Bs[kk][tx * FTN]);
            float4 bv1 = *reinterpret_cast<const float4*>(&Bs[kk][tx * FTN + 4]);
            float a[FTM] = {av0.x, av0.y, av0.z, av0.w, av1.x, av1.y, av1.z, av1.w};
            float b[FTN] = {bv0.x, bv0.y, bv0.z, bv0.w, bv1.x, bv1.y, bv1.z, bv1.w};
#pragma unroll
            for (int i = 0; i < FTM; ++i)
#pragma unroll
                for (int j = 0; j < FTN; ++j)
                    acc[i][j] = fmaf(a[i], b[j], acc[i][j]);
        }
        __syncthreads();
    }

#pragma unroll
    for (int i = 0; i < FTM; ++i) {
        float bv = acc[i][0];
        int bc = bn + tx * FTN;
#pragma unroll
        for (int j = 1; j < FTN; ++j) {
            float v = acc[i][j];
            int c = bn + tx * FTN + j;
            if (v > bv) { bv = v; bc = c; }
        }
        unsigned long long packed =
            ((unsigned long long)fkey(bv) << 32) |
            (unsigned long long)(0xFFFFFFFFu - (unsigned int)bc);
#pragma unroll
        for (int m = 1; m < 16; m <<= 1) {
            unsigned long long o = __shfl_xor(packed, m, 16);
            if (o > packed) packed = o;
        }
        if (tx == 0) atomicMax(&best[bm + ty * FTM + i], packed);
    }
}

__global__ void decode_kernel(const unsigned long long* __restrict__ best,
                              float* __restrict__ out, int N)
{
    int i = blockIdx.x * blockDim.x + threadIdx.x;
    if (i < N) {
        unsigned int inv = (unsigned int)(best[i] & 0xFFFFFFFFull);
        out[i] = (float)(0xFFFFFFFFu - inv);
    }
}

extern "C" void kernel_launch(void* const* d_in, const int* in_sizes, int n_in,
                              void* d_out, int out_size, void* d_ws, size_t ws_size,
                              hipStream_t stream) {
    const float* A = (const float*)d_in[0];   // x  [N, D]
    const float* B = (const float*)d_in[1];   // di [D, V]
    float* out = (float*)d_out;

    const int N = out_size;                   // 16384
    const int D = in_sizes[0] / N;            // 2048
    const int V = in_sizes[1] / D;            // 8192

    const size_t szXq = (size_t)N * D;                       // 32 MB fp8
    const size_t szDq = (size_t)D * V;                       // 16 MB fp8
    const size_t szDh = (size_t)D * V * sizeof(_Float16);    // 32 MB
    const size_t candsz = (size_t)N * 256 * 8;               // 32 MB
    const size_t need = szXq + szDq + 2 * szDh + candsz;     // ~146 MB

    if (ws_size >= need) {
        char* wsp = (char*)d_ws;
        unsigned char* Xq  = (unsigned char*)(wsp);
        unsigned char* DqT = (unsigned char*)(wsp + szXq);
        _Float16* DhT = (_Float16*)(wsp + szXq + szDq);
        _Float16* DlT = (_Float16*)(wsp + szXq + szDq + szDh);
        unsigned long long* cand =
            (unsigned long long*)(wsp + szXq + szDq + 2 * szDh);

        prep_x_q<<<(int)(((size_t)N * D) / (256 * 8)), 256, 0, stream>>>(A, Xq);
        prep_di_q<<<dim3(V / 64, D / 32), 256, 0, stream>>>(B, DqT, DhT, DlT, D, V);
        gemm_mx_top2<<<(N / 128) * (V / 128), 256, 0, stream>>>(
            Xq, DqT, cand, N, D, V);
        refine_kernel<<<(N + 3) / 4, 256, 0, stream>>>(
            cand, A, DhT, DlT, out, N, D, V);
    } else {
        unsigned long long* best = (unsigned long long*)d_ws;
        hipMemsetAsync(best, 0, (size_t)N * sizeof(unsigned long long), stream);
        gemm_argmax_fp32_kernel<<<dim3(V / 128, N / 128), 256, 0, stream>>>(A, B, best, N, D, V);
        decode_kernel<<<(N + 255) / 256, 256, 0, stream>>>(best, out, N);
    }
}